// Round 2
// baseline (10285.454 us; speedup 1.0000x reference)
//
#include <hip/hip_runtime.h>
#include <hip/hip_bf16.h>

#define B_  32
#define T_  512
#define I_  512
#define H_  1024
#define O_  360
#define H3_ 3072
#define M_  (B_*T_)      // 16384

static constexpr int GRU_NB = 64;   // blocks in GRU persistent kernel (16 units each)

typedef __bf16 bf16x8 __attribute__((ext_vector_type(8)));
typedef float  f32x4  __attribute__((ext_vector_type(4)));

__device__ __forceinline__ float sigmoidf_(float x) {
  return 1.0f / (1.0f + __expf(-x));
}

__device__ __forceinline__ float ld_f32(const float* p) { return *p; }
__device__ __forceinline__ float ld_f32(const __hip_bfloat16* p) { return __bfloat162float(*p); }
__device__ __forceinline__ void st_f32(float* p, float v) { *p = v; }
__device__ __forceinline__ void st_f32(__hip_bfloat16* p, float v) { *p = __float2bfloat16(v); }

// ---------------------------------------------------------------- utilities
__global__ void f32_to_bf16_k(const float* __restrict__ in,
                              __hip_bfloat16* __restrict__ out, int n) {
  int i = blockIdx.x * blockDim.x + threadIdx.x;
  int stride = gridDim.x * blockDim.x;
  for (; i < n; i += stride) out[i] = __float2bfloat16(in[i]);
}

__global__ void gru_init_k(__hip_bfloat16* __restrict__ hbuf,
                           unsigned* __restrict__ syncc) {
  int i = blockIdx.x * blockDim.x + threadIdx.x;
  int stride = gridDim.x * blockDim.x;
  for (; i < 2 * B_ * H_; i += stride) hbuf[i] = __float2bfloat16(0.0f);
  if (blockIdx.x == 0 && threadIdx.x == 0) *syncc = 0u;
}

// ---------------------------------------------------------------- fp32 GEMM
// C[M,N] = act(A[M,K] * W[N,K]^T + bias[N]);  ACT=1 -> relu
// A row stride = lda. M multiple of 128; K multiple of 8; N arbitrary.
template <int ACT, typename OT>
__global__ __launch_bounds__(256)
void sgemm_bt(const float* __restrict__ A, const float* __restrict__ W,
              const float* __restrict__ bias, OT* __restrict__ C,
              int M, int N, int K, int lda) {
  __shared__ float As[8][128];
  __shared__ float Ws[8][128];
  const int tid = threadIdx.x;
  const int bm = blockIdx.y * 128;
  const int bn = blockIdx.x * 128;
  const int tm = ((tid >> 4) & 15) << 3;   // 0..120
  const int tn = (tid & 15) << 3;          // 0..120
  const int lr = tid >> 1;                 // 0..127 staging row
  const int lc = (tid & 1) << 2;           // 0 or 4 staging k-offset

  float acc[8][8];
#pragma unroll
  for (int i = 0; i < 8; ++i)
#pragma unroll
    for (int j = 0; j < 8; ++j) acc[i][j] = 0.0f;

  const float* Ap = A + (size_t)(bm + lr) * lda + lc;
  const bool wok = (bn + lr) < N;
  const float* Wp = W + (size_t)(wok ? (bn + lr) : 0) * K + lc;

  for (int k0 = 0; k0 < K; k0 += 8) {
    float4 av = *(const float4*)(Ap + k0);
    float4 wv = make_float4(0.f, 0.f, 0.f, 0.f);
    if (wok) wv = *(const float4*)(Wp + k0);
    __syncthreads();   // previous tile fully consumed
    As[lc + 0][lr] = av.x; As[lc + 1][lr] = av.y;
    As[lc + 2][lr] = av.z; As[lc + 3][lr] = av.w;
    Ws[lc + 0][lr] = wv.x; Ws[lc + 1][lr] = wv.y;
    Ws[lc + 2][lr] = wv.z; Ws[lc + 3][lr] = wv.w;
    __syncthreads();
#pragma unroll
    for (int kk = 0; kk < 8; ++kk) {
      float a[8], w[8];
#pragma unroll
      for (int i = 0; i < 8; ++i) a[i] = As[kk][tm + i];
#pragma unroll
      for (int j = 0; j < 8; ++j) w[j] = Ws[kk][tn + j];
#pragma unroll
      for (int i = 0; i < 8; ++i)
#pragma unroll
        for (int j = 0; j < 8; ++j) acc[i][j] = fmaf(a[i], w[j], acc[i][j]);
    }
  }

#pragma unroll
  for (int j = 0; j < 8; ++j) {
    const int n = bn + tn + j;
    if (n < N) {
      const float bj = bias[n];
#pragma unroll
      for (int i = 0; i < 8; ++i) {
        float v = acc[i][j] + bj;
        if (ACT) v = fmaxf(v, 0.0f);
        st_f32(&C[(size_t)(bm + tm + i) * N + n], v);
      }
    }
  }
}

// ---------------------------------------------------------------- GRU scan
// Persistent kernel: 64 blocks x 128 threads. Block owns 16 hidden units.
// Wave 0 -> batch rows 0..15, wave 1 -> rows 16..31 (full K = 1024 each).
// fp32 hidden state stays in registers (lane owns its (b,u) cells); only the
// bf16 copy used as next step's A-operand goes through global memory.
// NOTE: xg and hs may ALIAS (fp32 path interleaves hs into xg's r columns);
// each (b,u,t) cell is read-then-written by the SAME thread, and neither
// pointer is __restrict__, so ordering is preserved.
template <typename XT>
__global__ __launch_bounds__(128)
void gru_scan(const XT* xg,                            // [B,T,3H]
              const __hip_bfloat16* __restrict__ Wbf,  // [3H][H] bf16
              const float* __restrict__ bhh,           // [3H]
              float* hs, int hs_ld,                    // [B,T,*] out (row stride hs_ld)
              __hip_bfloat16* __restrict__ hbuf,       // [2][B][H] bf16
              unsigned* __restrict__ syncc) {
  const int tid  = threadIdx.x;
  const int lane = tid & 63;
  const int bt   = tid >> 6;        // wave index = b-tile (0/1)
  const int col  = lane & 15;       // unit within block / A row within tile
  const int krow = lane >> 4;       // k-octet selector (0..3)
  const int u    = blockIdx.x * 16 + col;
  const int bb   = bt * 16 + krow * 4;   // C-row base -> batch index base

  const float bhr = bhh[u];
  const float bhz = bhh[H_ + u];
  const float bhn = bhh[2 * H_ + u];

  const bf16x8* Wv = (const bf16x8*)Wbf;          // 128 vectors per row
  const bf16x8* wr = Wv + (size_t)u * 128 + krow;
  const bf16x8* wz = wr + (size_t)H_ * 128;
  const bf16x8* wn = wz + (size_t)H_ * 128;

  f32x4 hold = {0.f, 0.f, 0.f, 0.f};

  for (int t = 0; t < T_; ++t) {
    const int cur = t & 1;
    const bf16x8* ap =
        (const bf16x8*)(hbuf + cur * (B_ * H_)) + (size_t)(bt * 16 + col) * 128 + krow;

    f32x4 ar = {0.f, 0.f, 0.f, 0.f};
    f32x4 az = {0.f, 0.f, 0.f, 0.f};
    f32x4 an = {0.f, 0.f, 0.f, 0.f};
#pragma unroll 8
    for (int ks = 0; ks < 32; ++ks) {
      bf16x8 a = ap[ks * 4];
      ar = __builtin_amdgcn_mfma_f32_16x16x32_bf16(a, wr[ks * 4], ar, 0, 0, 0);
      az = __builtin_amdgcn_mfma_f32_16x16x32_bf16(a, wz[ks * 4], az, 0, 0, 0);
      an = __builtin_amdgcn_mfma_f32_16x16x32_bf16(a, wn[ks * 4], an, 0, 0, 0);
    }

    __hip_bfloat16* hn_out = hbuf + (cur ^ 1) * (B_ * H_);
#pragma unroll
    for (int c = 0; c < 4; ++c) {
      const int b = bb + c;
      const XT* xp = xg + ((size_t)b * T_ + t) * H3_;
      const float r = sigmoidf_(ld_f32(xp + u) + ar[c] + bhr);
      const float z = sigmoidf_(ld_f32(xp + H_ + u) + az[c] + bhz);
      const float n = tanhf(ld_f32(xp + 2 * H_ + u) + r * (an[c] + bhn));
      const float h = (1.0f - z) * n + z * hold[c];
      hold[c] = h;
      hs[((size_t)b * T_ + t) * hs_ld + u] = h;
      hn_out[b * H_ + u] = __float2bfloat16(h);
    }

    // ---- grid barrier (monotonic counter; release/acquire at agent scope)
    __syncthreads();
    if (tid == 0) {
      __hip_atomic_fetch_add(syncc, 1u, __ATOMIC_ACQ_REL, __HIP_MEMORY_SCOPE_AGENT);
      const unsigned tgt = (unsigned)GRU_NB * (unsigned)(t + 1);
      while (__hip_atomic_load(syncc, __ATOMIC_ACQUIRE, __HIP_MEMORY_SCOPE_AGENT) < tgt) {
        __builtin_amdgcn_s_sleep(2);
      }
    }
    __syncthreads();
  }
}

// ---------------------------------------------------------------- launch
extern "C" void kernel_launch(void* const* d_in, const int* in_sizes, int n_in,
                              void* d_out, int out_size, void* d_ws, size_t ws_size,
                              hipStream_t stream) {
  const float* x    = (const float*)d_in[0];
  const float* W1   = (const float*)d_in[1];
  const float* b1   = (const float*)d_in[2];
  const float* W2   = (const float*)d_in[3];
  const float* b2   = (const float*)d_in[4];
  const float* Wih  = (const float*)d_in[5];
  const float* bih  = (const float*)d_in[6];
  const float* Whh  = (const float*)d_in[7];
  const float* bhh  = (const float*)d_in[8];
  const float* Wout = (const float*)d_in[9];
  const float* bout = (const float*)d_in[10];
  float* out = (float*)d_out;

  const size_t MB = (size_t)1 << 20;
  char* ws = (char*)d_ws;

  if (ws_size >= 256 * MB) {
    // ---------------- fp32-xg path (256 MiB) ----------------
    // [0,64M):   h2, later Wbf(6M)+hbuf(@8M)+syncc(@9M)
    // [64,256M): xg fp32 [M][3H]; h1 aliased at its start; hs interleaved in
    //            xg's r-gate columns (row stride 3H).
    float* h2 = (float*)ws;
    float* h1 = (float*)(ws + 64 * MB);
    float* xg = (float*)(ws + 64 * MB);
    __hip_bfloat16* Wbf  = (__hip_bfloat16*)ws;
    __hip_bfloat16* hbuf = (__hip_bfloat16*)(ws + 8 * MB);
    unsigned* syncc = (unsigned*)(ws + 9 * MB);
    float* hs = xg;  const int hs_ld = H3_;

    sgemm_bt<1, float><<<dim3(8, 128), 256, 0, stream>>>(x, W1, b1, h1, M_, H_, I_, I_);
    sgemm_bt<1, float><<<dim3(8, 128), 256, 0, stream>>>(h1, W2, b2, h2, M_, H_, H_, H_);
    sgemm_bt<0, float><<<dim3(24, 128), 256, 0, stream>>>(h2, Wih, bih, xg, M_, H3_, H_, H_);
    f32_to_bf16_k<<<768, 256, 0, stream>>>(Whh, Wbf, H3_ * H_);
    gru_init_k<<<32, 256, 0, stream>>>(hbuf, syncc);
    gru_scan<float><<<GRU_NB, 128, 0, stream>>>(xg, Wbf, bhh, hs, hs_ld, hbuf, syncc);
    sgemm_bt<0, float><<<dim3(3, 128), 256, 0, stream>>>(hs, Wout, bout, out, M_, O_, H_, hs_ld);
  } else if (ws_size >= 167 * MB) {
    // ---------------- bf16-xg fallback (167 MiB) ----------------
    // [0,64M):    h2, later hs fp32 [M][H]
    // [64,160M):  xg bf16 [M][3H]; h1 fp32 aliased at its start
    // [160,166M): Wbf ; [166M,+128K): hbuf ; then syncc
    float* h2 = (float*)ws;
    float* hs = (float*)ws;
    float* h1 = (float*)(ws + 64 * MB);
    __hip_bfloat16* xg   = (__hip_bfloat16*)(ws + 64 * MB);
    __hip_bfloat16* Wbf  = (__hip_bfloat16*)(ws + 160 * MB);
    __hip_bfloat16* hbuf = (__hip_bfloat16*)(ws + 166 * MB);
    unsigned* syncc = (unsigned*)(ws + 166 * MB + 256 * 1024);

    sgemm_bt<1, float><<<dim3(8, 128), 256, 0, stream>>>(x, W1, b1, h1, M_, H_, I_, I_);
    sgemm_bt<1, float><<<dim3(8, 128), 256, 0, stream>>>(h1, W2, b2, h2, M_, H_, H_, H_);
    sgemm_bt<0, __hip_bfloat16><<<dim3(24, 128), 256, 0, stream>>>(h2, Wih, bih, xg, M_, H3_, H_, H_);
    f32_to_bf16_k<<<768, 256, 0, stream>>>(Whh, Wbf, H3_ * H_);
    gru_init_k<<<32, 256, 0, stream>>>(hbuf, syncc);
    gru_scan<__hip_bfloat16><<<GRU_NB, 128, 0, stream>>>(xg, Wbf, bhh, hs, H_, hbuf, syncc);
    sgemm_bt<0, float><<<dim3(3, 128), 256, 0, stream>>>(hs, Wout, bout, out, M_, O_, H_, H_);
  }
  // else: insufficient workspace -> zeros (visible failure, tells us ws_size tier)
}

// Round 3
// 8748.117 us; speedup vs baseline: 1.1757x; 1.1757x over previous
//
#include <hip/hip_runtime.h>
#include <hip/hip_bf16.h>

#define B_  32
#define T_  512
#define I_  512
#define H_  1024
#define O_  360
#define H3_ 3072
#define M_  (B_*T_)      // 16384

static constexpr int GRU_NB = 64;   // blocks in GRU persistent kernel (16 units each)

typedef __bf16 bf16x8 __attribute__((ext_vector_type(8)));
typedef float  f32x4  __attribute__((ext_vector_type(4)));

__device__ __forceinline__ float sigmoidf_(float x) {
  return 1.0f / (1.0f + __expf(-x));
}

__device__ __forceinline__ float ld_f32(const float* p) { return *p; }
__device__ __forceinline__ float ld_f32(const __hip_bfloat16* p) { return __bfloat162float(*p); }
__device__ __forceinline__ void st_f32(float* p, float v) { *p = v; }
__device__ __forceinline__ void st_f32(__hip_bfloat16* p, float v) { *p = __float2bfloat16(v); }

__device__ __forceinline__ unsigned short bf16_bits(float f) {
  __hip_bfloat16 b = __float2bfloat16(f);
  return *reinterpret_cast<unsigned short*>(&b);
}

// ---------------------------------------------------------------- utilities
__global__ void f32_to_bf16_k(const float* __restrict__ in,
                              __hip_bfloat16* __restrict__ out, int n) {
  int i = blockIdx.x * blockDim.x + threadIdx.x;
  int stride = gridDim.x * blockDim.x;
  for (; i < n; i += stride) out[i] = __float2bfloat16(in[i]);
}

__global__ void gru_init_k(__hip_bfloat16* __restrict__ hbuf,
                           unsigned* __restrict__ syncc) {
  int i = blockIdx.x * blockDim.x + threadIdx.x;
  int stride = gridDim.x * blockDim.x;
  for (; i < 2 * B_ * H_; i += stride) hbuf[i] = __float2bfloat16(0.0f);
  if (blockIdx.x == 0 && threadIdx.x == 0) *syncc = 0u;
}

// ---------------------------------------------------------------- fp32 GEMM
// C[M,N] = act(A[M,K] * W[N,K]^T + bias[N]);  ACT=1 -> relu
// A row stride = lda. M multiple of 128; K multiple of 8; N arbitrary.
template <int ACT, typename OT>
__global__ __launch_bounds__(256)
void sgemm_bt(const float* __restrict__ A, const float* __restrict__ W,
              const float* __restrict__ bias, OT* __restrict__ C,
              int M, int N, int K, int lda) {
  __shared__ float As[8][128];
  __shared__ float Ws[8][128];
  const int tid = threadIdx.x;
  const int bm = blockIdx.y * 128;
  const int bn = blockIdx.x * 128;
  const int tm = ((tid >> 4) & 15) << 3;   // 0..120
  const int tn = (tid & 15) << 3;          // 0..120
  const int lr = tid >> 1;                 // 0..127 staging row
  const int lc = (tid & 1) << 2;           // 0 or 4 staging k-offset

  float acc[8][8];
#pragma unroll
  for (int i = 0; i < 8; ++i)
#pragma unroll
    for (int j = 0; j < 8; ++j) acc[i][j] = 0.0f;

  const float* Ap = A + (size_t)(bm + lr) * lda + lc;
  const bool wok = (bn + lr) < N;
  const float* Wp = W + (size_t)(wok ? (bn + lr) : 0) * K + lc;

  for (int k0 = 0; k0 < K; k0 += 8) {
    float4 av = *(const float4*)(Ap + k0);
    float4 wv = make_float4(0.f, 0.f, 0.f, 0.f);
    if (wok) wv = *(const float4*)(Wp + k0);
    __syncthreads();   // previous tile fully consumed
    As[lc + 0][lr] = av.x; As[lc + 1][lr] = av.y;
    As[lc + 2][lr] = av.z; As[lc + 3][lr] = av.w;
    Ws[lc + 0][lr] = wv.x; Ws[lc + 1][lr] = wv.y;
    Ws[lc + 2][lr] = wv.z; Ws[lc + 3][lr] = wv.w;
    __syncthreads();
#pragma unroll
    for (int kk = 0; kk < 8; ++kk) {
      float a[8], w[8];
#pragma unroll
      for (int i = 0; i < 8; ++i) a[i] = As[kk][tm + i];
#pragma unroll
      for (int j = 0; j < 8; ++j) w[j] = Ws[kk][tn + j];
#pragma unroll
      for (int i = 0; i < 8; ++i)
#pragma unroll
        for (int j = 0; j < 8; ++j) acc[i][j] = fmaf(a[i], w[j], acc[i][j]);
    }
  }

#pragma unroll
  for (int j = 0; j < 8; ++j) {
    const int n = bn + tn + j;
    if (n < N) {
      const float bj = bias[n];
#pragma unroll
      for (int i = 0; i < 8; ++i) {
        float v = acc[i][j] + bj;
        if (ACT) v = fmaxf(v, 0.0f);
        st_f32(&C[(size_t)(bm + tm + i) * N + n], v);
      }
    }
  }
}

// ---------------------------------------------------------------- GRU scan
// Persistent kernel: 64 blocks x 128 threads. Block owns 16 hidden units.
// Wave 0 -> batch rows 0..15, wave 1 -> rows 16..31 (full K = 1024 each).
// fp32 hidden state stays in registers; the bf16 copy for the next step's
// A-operand is exchanged through L3 via RELAXED agent-scope atomics (sc1,
// bypasses the non-coherent per-XCD L2s). No acq/rel fences anywhere ->
// no buffer_wbl2 / buffer_inv -> weights stay L2-resident across steps.
// Release ordering is hand-rolled: s_waitcnt vmcnt(0) drains the sc1 stores
// to L3 before the (relaxed) barrier-counter add.
// NOTE: xg and hs may ALIAS (fp32 path interleaves hs into xg's r columns);
// each (b,u,t) cell is read-then-written by the SAME thread.
template <typename XT>
__global__ __launch_bounds__(128)
void gru_scan(const XT* xg,                            // [B,T,3H]
              const __hip_bfloat16* __restrict__ Wbf,  // [3H][H] bf16
              const float* __restrict__ bhh,           // [3H]
              float* hs, int hs_ld,                    // [B,T,*] out (row stride hs_ld)
              __hip_bfloat16* hbuf,                    // [2][B][H] bf16
              unsigned* syncc) {
  const int tid  = threadIdx.x;
  const int lane = tid & 63;
  const int bt   = tid >> 6;        // wave index = b-tile (0/1)
  const int col  = lane & 15;       // unit within block / A row within tile
  const int krow = lane >> 4;       // k-octet selector (0..3)
  const int u    = blockIdx.x * 16 + col;
  const int bb   = bt * 16 + krow * 4;   // C-row base -> batch index base

  const float bhr = bhh[u];
  const float bhz = bhh[H_ + u];
  const float bhn = bhh[2 * H_ + u];

  const bf16x8* Wv = (const bf16x8*)Wbf;          // 128 vectors per row
  const bf16x8* wr = Wv + (size_t)u * 128 + krow;
  const bf16x8* wz = wr + (size_t)H_ * 128;
  const bf16x8* wn = wz + (size_t)H_ * 128;

  f32x4 hold = {0.f, 0.f, 0.f, 0.f};

  for (int t = 0; t < T_; ++t) {
    const int cur = t & 1;

    // ---- prefetch this step's input-gate projections (HBM latency hides
    //      under the MFMA phase below)
    float pxr[4], pxz[4], pxn[4];
#pragma unroll
    for (int c = 0; c < 4; ++c) {
      const XT* xp = xg + ((size_t)(bb + c) * T_ + t) * H3_;
      pxr[c] = ld_f32(xp + u);
      pxz[c] = ld_f32(xp + H_ + u);
      pxn[c] = ld_f32(xp + 2 * H_ + u);
    }

    // ---- recurrent matmul: A (h, bf16) via L2-bypassing relaxed atomic
    //      loads from L3; B (weights) via plain cached loads (L2-resident).
    // A row = batch (bt*16+col), row stride in u64 units = H_*2/8 = 256.
    const unsigned long long* ab =
        (const unsigned long long*)(hbuf + cur * (B_ * H_)) +
        (size_t)(bt * 16 + col) * 256 + krow * 2;

    f32x4 ar = {0.f, 0.f, 0.f, 0.f};
    f32x4 az = {0.f, 0.f, 0.f, 0.f};
    f32x4 an = {0.f, 0.f, 0.f, 0.f};
#pragma unroll 8
    for (int ks = 0; ks < 32; ++ks) {
      union { unsigned long long q[2]; bf16x8 v; } A;
      A.q[0] = __hip_atomic_load(ab + ks * 8 + 0, __ATOMIC_RELAXED, __HIP_MEMORY_SCOPE_AGENT);
      A.q[1] = __hip_atomic_load(ab + ks * 8 + 1, __ATOMIC_RELAXED, __HIP_MEMORY_SCOPE_AGENT);
      ar = __builtin_amdgcn_mfma_f32_16x16x32_bf16(A.v, wr[ks * 4], ar, 0, 0, 0);
      az = __builtin_amdgcn_mfma_f32_16x16x32_bf16(A.v, wz[ks * 4], az, 0, 0, 0);
      an = __builtin_amdgcn_mfma_f32_16x16x32_bf16(A.v, wn[ks * 4], an, 0, 0, 0);
    }

    // ---- gates + state update (fp32 master state in registers)
    float hv[4];
#pragma unroll
    for (int c = 0; c < 4; ++c) {
      const float r = sigmoidf_(pxr[c] + ar[c] + bhr);
      const float z = sigmoidf_(pxz[c] + az[c] + bhz);
      const float n = tanhf(pxn[c] + r * (an[c] + bhn));
      const float h = (1.0f - z) * n + z * hold[c];
      hold[c] = h;
      hv[c] = h;
      hs[((size_t)(bb + c) * T_ + t) * hs_ld + u] = h;   // plain cached store
    }

    // ---- publish bf16 h for next step: pack (u_even,u_odd) pairs via
    //      lane^1 shuffle -> 32-bit relaxed atomic stores (sc1, to L3).
    unsigned* hn32 = (unsigned*)(hbuf + (cur ^ 1) * (B_ * H_));
    const int ue2 = (u & ~1) >> 1;           // u32 column index
    const int c0 = (lane & 1) ? 2 : 0;       // even lane stores c=0,1; odd c=2,3
#pragma unroll
    for (int c = 0; c < 4; ++c) {
      const float other = __shfl_xor(hv[c], 1, 64);
      unsigned p;
      if (lane & 1)
        p = (unsigned)bf16_bits(other) | ((unsigned)bf16_bits(hv[c]) << 16);
      else
        p = (unsigned)bf16_bits(hv[c]) | ((unsigned)bf16_bits(other) << 16);
      if (c == c0 || c == c0 + 1)
        __hip_atomic_store(hn32 + (size_t)(bb + c) * 512 + ue2, p,
                           __ATOMIC_RELAXED, __HIP_MEMORY_SCOPE_AGENT);
    }

    // ---- grid barrier: drain sc1 stores to L3, then relaxed monotonic
    //      counter (no cache maintenance anywhere).
    asm volatile("s_waitcnt vmcnt(0)" ::: "memory");
    __syncthreads();
    if (tid == 0) {
      __hip_atomic_fetch_add(syncc, 1u, __ATOMIC_RELAXED, __HIP_MEMORY_SCOPE_AGENT);
      const unsigned tgt = (unsigned)GRU_NB * (unsigned)(t + 1);
      while (__hip_atomic_load(syncc, __ATOMIC_RELAXED, __HIP_MEMORY_SCOPE_AGENT) < tgt) {
        __builtin_amdgcn_s_sleep(1);
      }
    }
    __syncthreads();
  }
}

// ---------------------------------------------------------------- launch
extern "C" void kernel_launch(void* const* d_in, const int* in_sizes, int n_in,
                              void* d_out, int out_size, void* d_ws, size_t ws_size,
                              hipStream_t stream) {
  const float* x    = (const float*)d_in[0];
  const float* W1   = (const float*)d_in[1];
  const float* b1   = (const float*)d_in[2];
  const float* W2   = (const float*)d_in[3];
  const float* b2   = (const float*)d_in[4];
  const float* Wih  = (const float*)d_in[5];
  const float* bih  = (const float*)d_in[6];
  const float* Whh  = (const float*)d_in[7];
  const float* bhh  = (const float*)d_in[8];
  const float* Wout = (const float*)d_in[9];
  const float* bout = (const float*)d_in[10];
  float* out = (float*)d_out;

  const size_t MB = (size_t)1 << 20;
  char* ws = (char*)d_ws;

  if (ws_size >= 256 * MB) {
    // ---------------- fp32-xg path (256 MiB) ----------------
    // [0,64M):   h2, later Wbf(6M)+hbuf(@8M)+syncc(@9M)
    // [64,256M): xg fp32 [M][3H]; h1 aliased at its start; hs interleaved in
    //            xg's r-gate columns (row stride 3H).
    float* h2 = (float*)ws;
    float* h1 = (float*)(ws + 64 * MB);
    float* xg = (float*)(ws + 64 * MB);
    __hip_bfloat16* Wbf  = (__hip_bfloat16*)ws;
    __hip_bfloat16* hbuf = (__hip_bfloat16*)(ws + 8 * MB);
    unsigned* syncc = (unsigned*)(ws + 9 * MB);
    float* hs = xg;  const int hs_ld = H3_;

    sgemm_bt<1, float><<<dim3(8, 128), 256, 0, stream>>>(x, W1, b1, h1, M_, H_, I_, I_);
    sgemm_bt<1, float><<<dim3(8, 128), 256, 0, stream>>>(h1, W2, b2, h2, M_, H_, H_, H_);
    sgemm_bt<0, float><<<dim3(24, 128), 256, 0, stream>>>(h2, Wih, bih, xg, M_, H3_, H_, H_);
    f32_to_bf16_k<<<768, 256, 0, stream>>>(Whh, Wbf, H3_ * H_);
    gru_init_k<<<32, 256, 0, stream>>>(hbuf, syncc);
    gru_scan<float><<<GRU_NB, 128, 0, stream>>>(xg, Wbf, bhh, hs, hs_ld, hbuf, syncc);
    sgemm_bt<0, float><<<dim3(3, 128), 256, 0, stream>>>(hs, Wout, bout, out, M_, O_, H_, hs_ld);
  } else if (ws_size >= 167 * MB) {
    // ---------------- bf16-xg fallback (167 MiB) ----------------
    float* h2 = (float*)ws;
    float* hs = (float*)ws;
    float* h1 = (float*)(ws + 64 * MB);
    __hip_bfloat16* xg   = (__hip_bfloat16*)(ws + 64 * MB);
    __hip_bfloat16* Wbf  = (__hip_bfloat16*)(ws + 160 * MB);
    __hip_bfloat16* hbuf = (__hip_bfloat16*)(ws + 166 * MB);
    unsigned* syncc = (unsigned*)(ws + 166 * MB + 256 * 1024);

    sgemm_bt<1, float><<<dim3(8, 128), 256, 0, stream>>>(x, W1, b1, h1, M_, H_, I_, I_);
    sgemm_bt<1, float><<<dim3(8, 128), 256, 0, stream>>>(h1, W2, b2, h2, M_, H_, H_, H_);
    sgemm_bt<0, __hip_bfloat16><<<dim3(24, 128), 256, 0, stream>>>(h2, Wih, bih, xg, M_, H3_, H_, H_);
    f32_to_bf16_k<<<768, 256, 0, stream>>>(Whh, Wbf, H3_ * H_);
    gru_init_k<<<32, 256, 0, stream>>>(hbuf, syncc);
    gru_scan<__hip_bfloat16><<<GRU_NB, 128, 0, stream>>>(xg, Wbf, bhh, hs, H_, hbuf, syncc);
    sgemm_bt<0, float><<<dim3(3, 128), 256, 0, stream>>>(hs, Wout, bout, out, M_, O_, H_, H_);
  }
  // else: insufficient workspace -> zeros (visible failure, tells us ws_size tier)
}